// Round 1
// 473.006 us; speedup vs baseline: 1.1099x; 1.1099x over previous
//
#include <hip/hip_runtime.h>
#include <hip/hip_bf16.h>

// Problem constants
#define Mdim 2048
#define Ndim 8192
#define Kdim 8192
#define NT (Kdim / 64)   // 128 K-tiles of BK=64

typedef __bf16 bf16x8 __attribute__((ext_vector_type(8)));
typedef float f32x4 __attribute__((ext_vector_type(4)));
typedef unsigned short ushort8 __attribute__((ext_vector_type(8)));
typedef unsigned short ushort4v __attribute__((ext_vector_type(4)));

__device__ __forceinline__ unsigned short f2bf_rne(float f) {
    unsigned u = __float_as_uint(f);
    u += 0x7fffu + ((u >> 16) & 1u);
    return (unsigned short)(u >> 16);
}

__device__ __forceinline__ ushort8 decode8(unsigned bits, float4 c0, float4 c1) {
    ushort8 o;
#pragma unroll
    for (int i = 0; i < 8; ++i) {
        unsigned id = (bits >> (3 * i)) & 7u;
        float a0 = (id & 1) ? c0.y : c0.x;
        float a1 = (id & 1) ? c0.w : c0.z;
        float a2 = (id & 1) ? c1.y : c1.x;
        float a3 = (id & 1) ? c1.w : c1.z;
        float b0 = (id & 2) ? a1 : a0;
        float b1 = (id & 2) ? a3 : a2;
        float v  = (id & 4) ? b1 : b0;
        o[i] = f2bf_rne(v);
    }
    return o;
}

// ---------------------------------------------------------------------------
// Fused prep (unchanged this round): dequant + x fp32->bf16.
// ---------------------------------------------------------------------------
__global__ __launch_bounds__(256) void k_prep(const int* __restrict__ packed,
                                              const float* __restrict__ cb,
                                              const float* __restrict__ x,
                                              unsigned short* __restrict__ W,
                                              unsigned short* __restrict__ xb) {
    const int t = threadIdx.x;
    if (blockIdx.x < 16384) {
        const size_t th = (size_t)blockIdx.x * 256 + t;
        const size_t g0 = th * 2;
        const int2* pv = (const int2*)(packed + g0 * 3);
        int2 q0 = pv[0], q1 = pv[1], q2 = pv[2];
        unsigned bits0 = (unsigned)(q0.x & 255) | ((unsigned)(q0.y & 255) << 8) |
                         ((unsigned)(q1.x & 255) << 16);
        unsigned bits1 = (unsigned)(q1.y & 255) | ((unsigned)(q2.x & 255) << 8) |
                         ((unsigned)(q2.y & 255) << 16);
        const float4* cv0 = (const float4*)(cb + ((g0 >> 4) << 3));
        const float4* cv1 = (const float4*)(cb + (((g0 + 1) >> 4) << 3));
        float4 c00 = cv0[0], c01 = cv0[1];
        float4 c10 = cv1[0], c11 = cv1[1];
        ushort8 o0 = decode8(bits0, c00, c01);
        ushort8 o1 = decode8(bits1, c10, c11);
        unsigned short* wp = W + (g0 << 3);
        *(ushort8*)(wp)     = o0;
        *(ushort8*)(wp + 8) = o1;
    } else {
        const size_t u = (size_t)(blockIdx.x - 16384) * 256 + t;
        float4 a = ((const float4*)x)[u];
        ushort4v o;
        o[0] = f2bf_rne(a.x); o[1] = f2bf_rne(a.y);
        o[2] = f2bf_rne(a.z); o[3] = f2bf_rne(a.w);
        ((ushort4v*)xb)[u] = o;
    }
}

// ---------------------------------------------------------------------------
// 256x256 8-phase GEMM (T2+T3+T4+T5 port):
//   C[M,N] = A[M,K] * B[N,K]^T, bf16 in, fp32 out.
// 8 waves (2x4 per quadrant), 4 quadrant-phases per K-tile:
//   P1 (Alo,Blo) P2 (Alo,Bhi) P3 (Ahi,Bhi) P4 (Ahi,Blo)
// with A frags reused P1->P2 / P3->P4 and B-hi frags reused P2->P3.
// Staging: one half-tile per phase into the slot whose last LDS read was the
// previous phase; single counted s_waitcnt vmcnt(6) per K-tile (3 half-tiles
// = 6 global_load_lds stay in flight across barriers, never drained to 0).
// Raw s_barrier (memory-clobber asm) so the compiler never emits the
// vmcnt(0) drain that capped the old structure at ~870 TF.
// LDS XOR swizzle at 16B-chunk granularity via pre-swizzled global source
// (linear global_load_lds dest), same scheme as before: 0 bank conflicts.
// ---------------------------------------------------------------------------
__device__ __forceinline__ void gld16(const unsigned short* g, unsigned short* l) {
    __builtin_amdgcn_global_load_lds(
        (const __attribute__((address_space(1))) unsigned int*)g,
        (__attribute__((address_space(3))) unsigned int*)l, 16, 0, 0);
}

#define BAR()    asm volatile("s_barrier" ::: "memory")
#define FENCE()  asm volatile("" ::: "memory")
#define WAIT_DS0() asm volatile("s_waitcnt lgkmcnt(0)" ::: "memory")

__global__ __launch_bounds__(512, 2) void k_gemm(const unsigned short* __restrict__ A,
                                                 const unsigned short* __restrict__ B,
                                                 float* __restrict__ C) {
    __shared__ unsigned short LA[4 * 8192];   // [buf][half][128*64] = 64 KB
    __shared__ unsigned short LB[4 * 8192];   // 64 KB

    const int tid  = threadIdx.x;
    const int lane = tid & 63;
    const int wave = tid >> 6;               // 0..7
    const int qm = wave >> 2;                // 0..1 : 64-row strip in quadrant
    const int qn = wave & 3;                 // 0..3 : 32-col strip in quadrant

    // XCD-aware mapping: 256 blocks, block bid lands on XCD bid&7 (heuristic).
    // Each XCD owns one M-panel (A panel = 4 MB -> resident in its L2);
    // B panels shared across XCDs through L3 (128 MB < 256 MB).
    const int bid = blockIdx.x;
    const int bm = (bid & 7) * 256;
    const int bn = (bid >> 3) * 256;

    // Staging source addressing. Half-tile = 128 rows x 64 k (16 KB) staged by
    // 2 x gld16/thread; linear LDS dest chunk c*512+tid; source column
    // pre-swizzled: row r chunk slot s holds global chunk s ^ (r&7).
    const int chunk0 = tid, chunk1 = tid + 512;
    const int srow0 = chunk0 >> 3, srow1 = chunk1 >> 3;       // 0..63 / 64..127
    const int scol0 = ((chunk0 & 7) ^ (srow0 & 7)) * 8;
    const int scol1 = ((chunk1 & 7) ^ (srow1 & 7)) * 8;
    const unsigned short* Ag0 = A + (size_t)(bm + srow0) * Kdim + scol0;
    const unsigned short* Ag1 = A + (size_t)(bm + srow1) * Kdim + scol1;
    const unsigned short* Bg0 = B + (size_t)(bn + srow0) * Kdim + scol0;
    const unsigned short* Bg1 = B + (size_t)(bn + srow1) * Kdim + scol1;

#define STAGE_A(T, H, BUF) do {                                                   \
    unsigned short* _d = LA + ((BUF) * 2 + (H)) * 8192;                           \
    gld16(Ag0 + (size_t)(H) * 128 * Kdim + (size_t)(T) * 64, _d + (size_t)tid * 8);        \
    gld16(Ag1 + (size_t)(H) * 128 * Kdim + (size_t)(T) * 64, _d + (size_t)(tid + 512) * 8);\
    FENCE();                                                                      \
} while (0)
#define STAGE_B(T, H, BUF) do {                                                   \
    unsigned short* _d = LB + ((BUF) * 2 + (H)) * 8192;                           \
    gld16(Bg0 + (size_t)(H) * 128 * Kdim + (size_t)(T) * 64, _d + (size_t)tid * 8);        \
    gld16(Bg1 + (size_t)(H) * 128 * Kdim + (size_t)(T) * 64, _d + (size_t)(tid + 512) * 8);\
    FENCE();                                                                      \
} while (0)

    // Fragment read addressing (within a 128x64 slot, row-major, swizzled).
    const int r15 = lane & 15;
    const int q   = lane >> 4;               // 0..3
    const int rlo = r15 & 7;                 // frag rows are +16*i: row&7 const
    const int aro = qm * 64 + r15;           // + i*16
    const int bro = qn * 32 + r15;           // + j*16
    const int ch0 = ((0 + q) ^ rlo) * 8;     // kk=0 chunk (ushort offset)
    const int ch1 = ((4 + q) ^ rlo) * 8;     // kk=1 chunk

    f32x4 acc[4][4][2];
    const f32x4 zero = {0.f, 0.f, 0.f, 0.f};
#pragma unroll
    for (int p = 0; p < 4; ++p)
#pragma unroll
        for (int i = 0; i < 4; ++i)
#pragma unroll
            for (int j = 0; j < 2; ++j) acc[p][i][j] = zero;

    bf16x8 af[4][2], bf[2][2];

#define LOAD_A(BUF, H) do {                                                       \
    const unsigned short* _s = LA + ((BUF) * 2 + (H)) * 8192;                     \
    _Pragma("unroll") for (int i = 0; i < 4; ++i) {                               \
        int _r = (aro + i * 16) * 64;                                             \
        af[i][0] = *(const bf16x8*)&_s[_r + ch0];                                 \
        af[i][1] = *(const bf16x8*)&_s[_r + ch1];                                 \
    }                                                                             \
} while (0)
#define LOAD_B(BUF, H) do {                                                       \
    const unsigned short* _s = LB + ((BUF) * 2 + (H)) * 8192;                     \
    _Pragma("unroll") for (int j = 0; j < 2; ++j) {                               \
        int _r = (bro + j * 16) * 64;                                             \
        bf[j][0] = *(const bf16x8*)&_s[_r + ch0];                                 \
        bf[j][1] = *(const bf16x8*)&_s[_r + ch1];                                 \
    }                                                                             \
} while (0)

#define MFMA_PHASE(P) do {                                                        \
    __builtin_amdgcn_s_setprio(1);                                                \
    _Pragma("unroll") for (int i = 0; i < 4; ++i)                                 \
    _Pragma("unroll") for (int j = 0; j < 2; ++j) {                               \
        acc[P][i][j] = __builtin_amdgcn_mfma_f32_16x16x32_bf16(                   \
            af[i][0], bf[j][0], acc[P][i][j], 0, 0, 0);                           \
        acc[P][i][j] = __builtin_amdgcn_mfma_f32_16x16x32_bf16(                   \
            af[i][1], bf[j][1], acc[P][i][j], 0, 0, 0);                           \
    }                                                                             \
    __builtin_amdgcn_s_setprio(0);                                                \
} while (0)

// One K-tile = 4 phases. Staging stream per tile T (issued for T+2, plus
// B(T+1)lo at P1): Alo@P2, Bhi@P3, Ahi@P4, Blo@P1(next tile). Each stage
// targets the slot whose last LDS read was the previous phase. Single
// counted vmcnt per tile at end of P4 guarantees tile T+1 fully landed
// while 3 half-tiles for T+2 stay in flight.
#define KSTEP(T, BUF) do {                                                        \
    LOAD_A(BUF, 0); LOAD_B(BUF, 0);                                               \
    if ((T) + 1 < NT) STAGE_B((T) + 1, 0, (BUF) ^ 1);                             \
    BAR(); WAIT_DS0();                                                            \
    MFMA_PHASE(0);                                                                \
    BAR();                                                                        \
    LOAD_B(BUF, 1);                                                               \
    if ((T) + 2 < NT) STAGE_A((T) + 2, 0, BUF);                                   \
    BAR(); WAIT_DS0();                                                            \
    MFMA_PHASE(1);                                                                \
    BAR();                                                                        \
    LOAD_A(BUF, 1);                                                               \
    if ((T) + 2 < NT) STAGE_B((T) + 2, 1, BUF);                                   \
    BAR(); WAIT_DS0();                                                            \
    MFMA_PHASE(2);                                                                \
    BAR();                                                                        \
    LOAD_B(BUF, 0);                                                               \
    if ((T) + 2 < NT) STAGE_A((T) + 2, 1, BUF);                                   \
    BAR(); WAIT_DS0();                                                            \
    MFMA_PHASE(3);                                                                \
    if ((T) + 2 < NT) { asm volatile("s_waitcnt vmcnt(6)" ::: "memory"); }        \
    else              { asm volatile("s_waitcnt vmcnt(0)" ::: "memory"); }        \
    BAR();                                                                        \
} while (0)

    // Prologue: tile0 complete (Alo,Bhi,Ahi,Blo) + tile1 Alo,Bhi,Ahi.
    // vmcnt(6): tile0 landed, 3 half-tiles of tile1 in flight (steady state).
    STAGE_A(0, 0, 0); STAGE_B(0, 1, 0); STAGE_A(0, 1, 0); STAGE_B(0, 0, 0);
    STAGE_A(1, 0, 1); STAGE_B(1, 1, 1); STAGE_A(1, 1, 1);
    asm volatile("s_waitcnt vmcnt(6)" ::: "memory");
    BAR();

    for (int t2 = 0; t2 < NT; t2 += 2) {
        KSTEP(t2, 0);
        KSTEP(t2 + 1, 1);
    }

    // Epilogue. Quadrant p: rows half RH[p], cols half CH[p].
    // C/D layout: col = lane&15, row = (lane>>4)*4 + r  (m89/m91).
    constexpr int RHs[4] = {0, 0, 1, 1};
    constexpr int CHs[4] = {0, 1, 1, 0};
#pragma unroll
    for (int p = 0; p < 4; ++p) {
#pragma unroll
        for (int i = 0; i < 4; ++i) {
#pragma unroll
            for (int j = 0; j < 2; ++j) {
                int row = bm + RHs[p] * 128 + qm * 64 + i * 16 + q * 4;
                int col = bn + CHs[p] * 128 + qn * 32 + j * 16 + r15;
                float* outp = C + (size_t)row * Ndim + col;
#pragma unroll
                for (int r = 0; r < 4; ++r)
                    outp[(size_t)r * Ndim] = acc[p][i][j][r];
            }
        }
    }

#undef STAGE_A
#undef STAGE_B
#undef LOAD_A
#undef LOAD_B
#undef MFMA_PHASE
#undef KSTEP
}

// ---------------------------------------------------------------------------
extern "C" void kernel_launch(void* const* d_in, const int* in_sizes, int n_in,
                              void* d_out, int out_size, void* d_ws, size_t ws_size,
                              hipStream_t stream) {
    const float* x      = (const float*)d_in[0];   // 2048 x 8192 fp32
    const int*   packed = (const int*)d_in[1];     // 25165824 int32 (one byte each)
    const float* cb     = (const float*)d_in[2];   // 524288 x 8 fp32
    float* out = (float*)d_out;                    // 2048 x 8192 fp32

    unsigned short* Wb = (unsigned short*)d_ws;                          // 128 MB bf16 W
    unsigned short* Xb = (unsigned short*)d_ws + (size_t)Ndim * Kdim;    // 32 MB bf16 x

    // 1) fused prep: dequant (blocks 0..16383) + x convert (16384..32767)
    k_prep<<<32768, 256, 0, stream>>>(packed, cb, x, Wb, Xb);
    // 2) GEMM: 256 blocks (1/CU), 512 threads, 128 KB static LDS
    k_gemm<<<dim3(256), 512, 0, stream>>>(Xb, Wb, out);
}

// Round 2
// 471.272 us; speedup vs baseline: 1.1139x; 1.0037x over previous
//
#include <hip/hip_runtime.h>
#include <hip/hip_bf16.h>

// Problem constants
#define Mdim 2048
#define Ndim 8192
#define Kdim 8192
#define NT (Kdim / 64)   // 128 K-tiles of BK=64

typedef __bf16 bf16x8 __attribute__((ext_vector_type(8)));
typedef float f32x4 __attribute__((ext_vector_type(4)));
typedef unsigned short ushort8 __attribute__((ext_vector_type(8)));
typedef unsigned short ushort4v __attribute__((ext_vector_type(4)));

__device__ __forceinline__ unsigned short f2bf_rne(float f) {
    unsigned u = __float_as_uint(f);
    u += 0x7fffu + ((u >> 16) & 1u);
    return (unsigned short)(u >> 16);
}

__device__ __forceinline__ ushort8 decode8(unsigned bits, float4 c0, float4 c1) {
    ushort8 o;
#pragma unroll
    for (int i = 0; i < 8; ++i) {
        unsigned id = (bits >> (3 * i)) & 7u;
        float a0 = (id & 1) ? c0.y : c0.x;
        float a1 = (id & 1) ? c0.w : c0.z;
        float a2 = (id & 1) ? c1.y : c1.x;
        float a3 = (id & 1) ? c1.w : c1.z;
        float b0 = (id & 2) ? a1 : a0;
        float b1 = (id & 2) ? a3 : a2;
        float v  = (id & 4) ? b1 : b0;
        o[i] = f2bf_rne(v);
    }
    return o;
}

// ---------------------------------------------------------------------------
// Fused prep, r2: dequant now 4 groups/thread via 3 x dwordx4 loads (halves
// load-instruction count vs 2-group/3x dwordx2; one codebook load per thread
// since 4 aligned groups always share a block). x convert unchanged.
// ---------------------------------------------------------------------------
__global__ __launch_bounds__(256) void k_prep(const int* __restrict__ packed,
                                              const float* __restrict__ cb,
                                              const float* __restrict__ x,
                                              unsigned short* __restrict__ W,
                                              unsigned short* __restrict__ xb) {
    const int t = threadIdx.x;
    if (blockIdx.x < 8192) {
        const size_t th = (size_t)blockIdx.x * 256 + t;    // 0..2097151
        const size_t g0 = th * 4;                          // group base (%4==0)
        const int4* pv = (const int4*)(packed + g0 * 3);   // 12 ints, 16B aligned
        int4 q0 = pv[0], q1 = pv[1], q2 = pv[2];
        unsigned bits0 = (unsigned)(q0.x & 255) | ((unsigned)(q0.y & 255) << 8) |
                         ((unsigned)(q0.z & 255) << 16);
        unsigned bits1 = (unsigned)(q0.w & 255) | ((unsigned)(q1.x & 255) << 8) |
                         ((unsigned)(q1.y & 255) << 16);
        unsigned bits2 = (unsigned)(q1.z & 255) | ((unsigned)(q1.w & 255) << 8) |
                         ((unsigned)(q2.x & 255) << 16);
        unsigned bits3 = (unsigned)(q2.y & 255) | ((unsigned)(q2.z & 255) << 8) |
                         ((unsigned)(q2.w & 255) << 16);
        // groups g0..g0+3 share one codebook block: g0%16 in {0,4,8,12}
        const float4* cv = (const float4*)(cb + ((g0 >> 4) << 3));
        float4 c0 = cv[0], c1 = cv[1];
        unsigned short* wp = W + (g0 << 3);                // 64B contiguous
        *(ushort8*)(wp)      = decode8(bits0, c0, c1);
        *(ushort8*)(wp + 8)  = decode8(bits1, c0, c1);
        *(ushort8*)(wp + 16) = decode8(bits2, c0, c1);
        *(ushort8*)(wp + 24) = decode8(bits3, c0, c1);
    } else {
        const size_t u = (size_t)(blockIdx.x - 8192) * 256 + t;  // 0..4194303
        float4 a = ((const float4*)x)[u];
        ushort4v o;
        o[0] = f2bf_rne(a.x); o[1] = f2bf_rne(a.y);
        o[2] = f2bf_rne(a.z); o[3] = f2bf_rne(a.w);
        ((ushort4v*)xb)[u] = o;
    }
}

// ---------------------------------------------------------------------------
// 256x256 GEMM, r2: one-phase-ahead LDS->reg pipelining.
// Every MFMA cluster's fragments were ds_read in a PREVIOUS phase, so the
// compiler's auto lgkm waits are already satisfied; LDS read time hides
// under MFMA instead of preceding it. Reads/tile/wave: 24 b128 (was 28;
// B-lo no longer read twice). One barrier per phase (4/tile, was 8).
// A uses a single 32-VGPR set: Ahi overwrites Alo's regs after Alo's last
// use (P1 MFMA), pinned by sched_barrier(0); Alo(T+1) likewise after P3.
// B double-buffered in regs by tile parity (bX/bY).
// vmcnt ledger (steady state, stage order Ahi(T+1)@P0, Blo(T+2)@P1,
// Bhi(T+2)@P2, Alo(T+2)@P3, 2 loads per stage):
//   P0: vmcnt(6) forces Ahi(T)   (read at P1-end, after end-P0 barrier)
//   P1: vmcnt(4) forces B(T+1)   (read at P2-start, after end-P1 barrier)
//   P2: vmcnt(4) forces Alo(T+1) (read at P3-end, after end-P2 barrier)
//   P3: none (Ahi(T+1) forced by next P0's vmcnt)
// Tail counts adjusted where stages are skipped.
// WAR safety (1 barrier/phase): every slot's overwrite is issued >= 1 full
// barrier after the slot's reads complete (reads complete before their
// first-use MFMA, which precedes that phase's end barrier).
// ---------------------------------------------------------------------------
__device__ __forceinline__ void gld16(const unsigned short* g, unsigned short* l) {
    __builtin_amdgcn_global_load_lds(
        (const __attribute__((address_space(1))) unsigned int*)g,
        (__attribute__((address_space(3))) unsigned int*)l, 16, 0, 0);
}

#define BAR()    asm volatile("s_barrier" ::: "memory")
#define FENCE()  asm volatile("" ::: "memory")
#define SBAR0()  __builtin_amdgcn_sched_barrier(0)
#define VMCNT(n) asm volatile("s_waitcnt vmcnt(" #n ")" ::: "memory")

__global__ __launch_bounds__(512, 2) void k_gemm(const unsigned short* __restrict__ A,
                                                 const unsigned short* __restrict__ B,
                                                 float* __restrict__ C) {
    __shared__ unsigned short LA[4 * 8192];   // [buf][half][128*64] = 64 KB
    __shared__ unsigned short LB[4 * 8192];   // 64 KB

    const int tid  = threadIdx.x;
    const int lane = tid & 63;
    const int wave = tid >> 6;               // 0..7
    const int qm = wave >> 2;                // 0..1
    const int qn = wave & 3;                 // 0..3

    // XCD-aware mapping: each XCD owns one M-panel (A panel L2-resident).
    const int bid = blockIdx.x;
    const int bm = (bid & 7) * 256;
    const int bn = (bid >> 3) * 256;

    // Staging: half-tile = 128 rows x 64 k (16 KB), 2 gld16/thread, source
    // column pre-swizzled (slot s of row r holds global chunk s ^ (r&7)).
    const int chunk0 = tid, chunk1 = tid + 512;
    const int srow0 = chunk0 >> 3, srow1 = chunk1 >> 3;
    const int scol0 = ((chunk0 & 7) ^ (srow0 & 7)) * 8;
    const int scol1 = ((chunk1 & 7) ^ (srow1 & 7)) * 8;
    const unsigned short* Ag0 = A + (size_t)(bm + srow0) * Kdim + scol0;
    const unsigned short* Ag1 = A + (size_t)(bm + srow1) * Kdim + scol1;
    const unsigned short* Bg0 = B + (size_t)(bn + srow0) * Kdim + scol0;
    const unsigned short* Bg1 = B + (size_t)(bn + srow1) * Kdim + scol1;

#define STAGE_A(T, H, BUF) do {                                                   \
    unsigned short* _d = LA + ((BUF) * 2 + (H)) * 8192;                           \
    gld16(Ag0 + (size_t)(H) * 128 * Kdim + (size_t)(T) * 64, _d + (size_t)tid * 8);        \
    gld16(Ag1 + (size_t)(H) * 128 * Kdim + (size_t)(T) * 64, _d + (size_t)(tid + 512) * 8);\
    FENCE();                                                                      \
} while (0)
#define STAGE_B(T, H, BUF) do {                                                   \
    unsigned short* _d = LB + ((BUF) * 2 + (H)) * 8192;                           \
    gld16(Bg0 + (size_t)(H) * 128 * Kdim + (size_t)(T) * 64, _d + (size_t)tid * 8);        \
    gld16(Bg1 + (size_t)(H) * 128 * Kdim + (size_t)(T) * 64, _d + (size_t)(tid + 512) * 8);\
    FENCE();                                                                      \
} while (0)

    const int r15 = lane & 15;
    const int q   = lane >> 4;
    const int rlo = r15 & 7;
    const int aro = qm * 64 + r15;
    const int bro = qn * 32 + r15;
    const int ch0 = ((0 + q) ^ rlo) * 8;
    const int ch1 = ((4 + q) ^ rlo) * 8;

    f32x4 acc[4][4][2];
    const f32x4 zero = {0.f, 0.f, 0.f, 0.f};
#pragma unroll
    for (int p = 0; p < 4; ++p)
#pragma unroll
        for (int i = 0; i < 4; ++i)
#pragma unroll
            for (int j = 0; j < 2; ++j) acc[p][i][j] = zero;

    bf16x8 aF[4][2];          // single A set: holds lo, then hi (reg reuse)
    bf16x8 bX[2][2][2];       // [half][j][kk] current-parity B
    bf16x8 bY[2][2][2];       // next-parity B

#define LOAD_AF(BUF, H) do {                                                      \
    const unsigned short* _s = LA + ((BUF) * 2 + (H)) * 8192;                     \
    _Pragma("unroll") for (int i = 0; i < 4; ++i) {                               \
        int _r = (aro + i * 16) * 64;                                             \
        aF[i][0] = *(const bf16x8*)&_s[_r + ch0];                                 \
        aF[i][1] = *(const bf16x8*)&_s[_r + ch1];                                 \
    }                                                                             \
} while (0)
#define LOAD_BALL(BUF, BSET) do {                                                 \
    _Pragma("unroll") for (int _h = 0; _h < 2; ++_h) {                            \
        const unsigned short* _s = LB + ((BUF) * 2 + _h) * 8192;                  \
        _Pragma("unroll") for (int j = 0; j < 2; ++j) {                           \
            int _r = (bro + j * 16) * 64;                                         \
            BSET[_h][j][0] = *(const bf16x8*)&_s[_r + ch0];                       \
            BSET[_h][j][1] = *(const bf16x8*)&_s[_r + ch1];                       \
        }                                                                         \
    }                                                                             \
} while (0)

#define MFMA_PH(P, BSET, H) do {                                                  \
    __builtin_amdgcn_s_setprio(1);                                                \
    _Pragma("unroll") for (int i = 0; i < 4; ++i)                                 \
    _Pragma("unroll") for (int j = 0; j < 2; ++j) {                               \
        acc[P][i][j] = __builtin_amdgcn_mfma_f32_16x16x32_bf16(                   \
            aF[i][0], BSET[(H)][j][0], acc[P][i][j], 0, 0, 0);                    \
        acc[P][i][j] = __builtin_amdgcn_mfma_f32_16x16x32_bf16(                   \
            aF[i][1], BSET[(H)][j][1], acc[P][i][j], 0, 0, 0);                    \
    }                                                                             \
    __builtin_amdgcn_s_setprio(0);                                                \
} while (0)

// Quadrants: P0 = Alo x Blo, P1 = Alo x Bhi, P2 = Ahi x Bhi, P3 = Ahi x Blo.
#define KSTEP(T, BUF, BCUR, BNXT) do {                                            \
    /* P0 */                                                                      \
    if ((T) + 1 < NT) { VMCNT(6); STAGE_A((T) + 1, 1, (BUF) ^ 1); }               \
    else              { VMCNT(0); }                                               \
    MFMA_PH(0, BCUR, 0);                                                          \
    BAR();                                                                        \
    /* P1 */                                                                      \
    if ((T) + 1 < NT) { VMCNT(4); }                                               \
    if ((T) + 2 < NT) STAGE_B((T) + 2, 0, BUF);                                   \
    MFMA_PH(1, BCUR, 1);                                                          \
    SBAR0();                                                                      \
    LOAD_AF(BUF, 1);              /* Ahi(T) into aF (Alo dead after P1) */        \
    BAR();                                                                        \
    /* P2 */                                                                      \
    if ((T) + 1 < NT) {                                                           \
        if ((T) + 2 < NT) { VMCNT(4); } else { VMCNT(2); }                        \
        LOAD_BALL((BUF) ^ 1, BNXT);                                               \
    }                                                                             \
    if ((T) + 2 < NT) STAGE_B((T) + 2, 1, BUF);                                   \
    MFMA_PH(2, BCUR, 1);                                                          \
    BAR();                                                                        \
    /* P3 */                                                                      \
    if ((T) + 2 < NT) STAGE_A((T) + 2, 0, BUF);                                   \
    MFMA_PH(3, BCUR, 0);                                                          \
    SBAR0();                                                                      \
    if ((T) + 1 < NT) LOAD_AF((BUF) ^ 1, 0);   /* Alo(T+1) into aF */             \
    BAR();                                                                        \
} while (0)

    // Prologue: tile0 complete + tile1 {Blo,Bhi,Alo} (Ahi(1) staged at P0 of
    // tile 0). vmcnt(8): 14 loads outstanding -> oldest 6 (Blo0,Bhi0,Alo0)
    // landed for the pre-reads; Ahi0 forced by first P0's vmcnt(6).
    STAGE_B(0, 0, 0); STAGE_B(0, 1, 0); STAGE_A(0, 0, 0); STAGE_A(0, 1, 0);
    STAGE_B(1, 0, 1); STAGE_B(1, 1, 1); STAGE_A(1, 0, 1);
    asm volatile("s_waitcnt vmcnt(8)" ::: "memory");
    BAR();
    LOAD_BALL(0, bX);      // B(0) both halves
    LOAD_AF(0, 0);         // Alo(0)

    for (int t2 = 0; t2 < NT; t2 += 2) {
        KSTEP(t2, 0, bX, bY);
        KSTEP(t2 + 1, 1, bY, bX);
    }

    // Epilogue. Quadrant p: rows half RH[p], cols half CH[p].
    // C/D layout: col = lane&15, row = (lane>>4)*4 + r  (m89/m91).
    constexpr int RHs[4] = {0, 0, 1, 1};
    constexpr int CHs[4] = {0, 1, 1, 0};
#pragma unroll
    for (int p = 0; p < 4; ++p) {
#pragma unroll
        for (int i = 0; i < 4; ++i) {
#pragma unroll
            for (int j = 0; j < 2; ++j) {
                int row = bm + RHs[p] * 128 + qm * 64 + i * 16 + q * 4;
                int col = bn + CHs[p] * 128 + qn * 32 + j * 16 + r15;
                float* outp = C + (size_t)row * Ndim + col;
#pragma unroll
                for (int r = 0; r < 4; ++r)
                    outp[(size_t)r * Ndim] = acc[p][i][j][r];
            }
        }
    }

#undef STAGE_A
#undef STAGE_B
#undef LOAD_AF
#undef LOAD_BALL
#undef MFMA_PH
#undef KSTEP
}

// ---------------------------------------------------------------------------
extern "C" void kernel_launch(void* const* d_in, const int* in_sizes, int n_in,
                              void* d_out, int out_size, void* d_ws, size_t ws_size,
                              hipStream_t stream) {
    const float* x      = (const float*)d_in[0];   // 2048 x 8192 fp32
    const int*   packed = (const int*)d_in[1];     // 25165824 int32 (one byte each)
    const float* cb     = (const float*)d_in[2];   // 524288 x 8 fp32
    float* out = (float*)d_out;                    // 2048 x 8192 fp32

    unsigned short* Wb = (unsigned short*)d_ws;                          // 128 MB bf16 W
    unsigned short* Xb = (unsigned short*)d_ws + (size_t)Ndim * Kdim;    // 32 MB bf16 x

    // 1) fused prep: dequant (blocks 0..8191, 4 groups/thread) + x convert
    k_prep<<<24576, 256, 0, stream>>>(packed, cb, x, Wb, Xb);
    // 2) GEMM: 256 blocks (1/CU), 512 threads, 128 KB static LDS
    k_gemm<<<dim3(256), 512, 0, stream>>>(Xb, Wb, out);
}